// Round 6
// baseline (1072.747 us; speedup 1.0000x reference)
//
#include <hip/hip_runtime.h>
#include <hip/hip_bf16.h>

// Problem constants (fixed by reference)
#define SEQ 784
#define BS  256
#define DH  512
#define MT  (SEQ * BS)   // 200704 rows
#define NL  3
#define NC  14           // scan chunks
#define CL  56           // chunk length (NC*CL == SEQ)
#define COLS (BS * DH)   // 131072 = 2^17

typedef unsigned short u16;
typedef __bf16  bf16x8  __attribute__((ext_vector_type(8)));
typedef float   f32x4   __attribute__((ext_vector_type(4)));
typedef unsigned short ushort8 __attribute__((ext_vector_type(8)));

__device__ __forceinline__ u16 f2b(float f) {
    unsigned int x = __float_as_uint(f);
    unsigned int r = (x + 0x7FFFu + ((x >> 16) & 1u)) >> 16;   // RNE
    return (u16)r;
}
__device__ __forceinline__ float b2f(u16 u) {
    return __uint_as_float(((unsigned int)u) << 16);
}

// ---------------------------------------------------------------------------
// prep: pack B[l],C[l] (f32 (l,k,n)) -> bf16 MFMA-fragment order:
//   flat = ((((g*8 + wid)*4 + ni)*64 + lane)*8 + e
//   n = wid*64 + ni*16 + (lane&15);  k = g*32 + (lane>>4)*8 + e
// so a wave's B-fragment load is one coalesced global_load_dwordx4.
// ---------------------------------------------------------------------------
__global__ __launch_bounds__(256) void prep_k(const float* __restrict__ B,
                                              const float* __restrict__ C,
                                              u16* __restrict__ Bp,
                                              u16* __restrict__ Cp)
{
    const long t = (long)blockIdx.x * 256 + threadIdx.x;   // 0 .. 3*2^18-1
    const int  e  = (int)(t & 7);
    const int  l  = (int)((t >> 3) & 63);
    const int  ni = (int)((t >> 9) & 3);
    const int  wd = (int)((t >> 11) & 7);
    const int  g  = (int)((t >> 14) & 15);
    const long lay = t >> 18;
    const int  n = wd * 64 + ni * 16 + (l & 15);
    const int  k = g * 32 + (l >> 4) * 8 + e;
    const long src = (lay << 18) + (long)k * DH + n;
    Bp[t] = f2b(B[src]);
    Cp[t] = f2b(C[src]);
}

// ---------------------------------------------------------------------------
// h0 = relu(x * W0 + b0): one thread per 8 output cols
// ---------------------------------------------------------------------------
__global__ __launch_bounds__(256) void h0_k(const float* __restrict__ x,
                                            const float* __restrict__ W0,
                                            const float* __restrict__ b0,
                                            u16* __restrict__ out)
{
    const long t  = (long)blockIdx.x * 256 + threadIdx.x;  // 0 .. MT*64-1
    const long m  = t >> 6;
    const int  j0 = (int)(t & 63) * 8;
    const float xv = x[m];
    ushort8 o;
#pragma unroll
    for (int j = 0; j < 8; ++j)
        o[j] = f2b(fmaxf(fmaf(xv, W0[j0 + j], b0[j0 + j]), 0.f));
    *(ushort8*)&out[m * DH + j0] = o;
}

// ---------------------------------------------------------------------------
// In-place GEMM: Y(M,512) = [relu](X(M,512) @ W).
//  - FULL 64x512 A panel staged ONCE into LDS (8 gload_lds issues, one
//    __syncthreads). NO barriers and no A-staging in the K-loop, so the
//    compiler freely pipelines the L2-hot B-register loads across the
//    fully-unrolled K-loop (no older vmcnt entries to collateral-drain —
//    R5's stall mechanism is gone). Cross-block TLP hides the HBM stream.
//  - W fragment-packed (Wp): B-operands are coalesced dwordx4 from L2.
//  - A-swizzle retained (source pre-swizzle + XOR read; conflicts ~0).
//  - LDS 64KB: A panel aliased with the epilogue C-tile -> 2 blocks/CU.
// In-place safe: block owns rows [bm,bm+64) exclusively.
// ---------------------------------------------------------------------------
template <int RELU>
__global__ __launch_bounds__(512, 4) void gemm_ip(const u16* __restrict__ X,
                                                  const u16* __restrict__ Wp,
                                                  u16* __restrict__ Y)
{
    __shared__ __align__(16) u16 lds[64 * 512];   // 64 KB: A panel, then C tile

    const int tid  = threadIdx.x;
    const int lane = tid & 63;
    const int wid  = tid >> 6;                 // 0..7 -> 64-col block
    const long bm  = (long)blockIdx.x * 64;

    const int srow = tid >> 3;                 // staging row 0..63
    const int scol = (((tid & 7) ^ (srow & 7)) * 8);   // swizzled source col
    const u16* gax = X + (bm + srow) * DH + scol;

    // stage the ENTIRE A panel: sub-tile t = rows[0..64) x k[t*64..t*64+64)
#pragma unroll
    for (int t = 0; t < 8; ++t) {
        __builtin_amdgcn_global_load_lds(
            (const __attribute__((address_space(1))) void*)(gax + t * 64),
            (__attribute__((address_space(3))) void*)
                ((__attribute__((address_space(3))) char*)lds + t * 8192 + tid * 16),
            16, 0, 0);
    }

    f32x4 acc[4][4];
#pragma unroll
    for (int i = 0; i < 4; ++i)
#pragma unroll
        for (int j = 0; j < 4; ++j)
            acc[i][j] = (f32x4){0.f, 0.f, 0.f, 0.f};

    __syncthreads();   // drains the panel stage (vmcnt 0) once

#pragma unroll
    for (int t = 0; t < 8; ++t) {
        const u16* Atile = lds + t * 4096;
#pragma unroll
        for (int kk = 0; kk < 2; ++kk) {
            // B fragments straight from L2 (fragment-packed, coalesced)
            bf16x8 bv[4];
#pragma unroll
            for (int ni = 0; ni < 4; ++ni)
                bv[ni] = *(const bf16x8*)&Wp[((long)((2 * t + kk) * 32 + wid * 4 + ni) << 9)
                                             + (lane << 3)];
            // A fragments from LDS (swizzled read)
            const int fcol = ((kk * 4 + (lane >> 4)) ^ (lane & 7)) * 8;
            bf16x8 af[4];
#pragma unroll
            for (int i = 0; i < 4; ++i)
                af[i] = *(const bf16x8*)&Atile[(i * 16 + (lane & 15)) * 64 + fcol];
#pragma unroll
            for (int mi = 0; mi < 4; ++mi)
#pragma unroll
                for (int ni = 0; ni < 4; ++ni)
                    acc[mi][ni] = __builtin_amdgcn_mfma_f32_16x16x32_bf16(
                        af[mi], bv[ni], acc[mi][ni], 0, 0, 0);
        }
    }
    __syncthreads();   // all waves done reading A panel before C-tile overwrite

    // ---- Epilogue: stage C tile in LDS for coalesced stores.
    // C/D layout (m89): col = lane&15, row = (lane>>4)*4 + reg.
    // Row-group swizzle: col ^= ((row>>2)&3)*16.
    u16* Ctile = lds;   // 64 rows x 512 cols
    const int rbase = (lane >> 4) * 4;
    const int cloc  = wid * 64 + (lane & 15);
#pragma unroll
    for (int mi = 0; mi < 4; ++mi)
#pragma unroll
        for (int ni = 0; ni < 4; ++ni)
#pragma unroll
            for (int r = 0; r < 4; ++r) {
                float v = acc[mi][ni][r];
                if (RELU) v = fmaxf(v, 0.f);
                const int row = mi * 16 + rbase + r;
                const int col = (cloc + ni * 16) ^ (((row >> 2) & 3) * 16);
                Ctile[row * 512 + col] = f2b(v);
            }
    __syncthreads();
#pragma unroll
    for (int p = 0; p < 8; ++p) {
        const int e   = p * 4096 + tid * 8;    // logical element index
        const int row = e >> 9;
        const int col = e & 511;
        const int csw = col ^ (((row >> 2) & 3) * 16);
        *(ushort8*)&Y[(bm + row) * DH + col] = *(const ushort8*)&Ctile[row * 512 + csw];
    }
}

// ---------------------------------------------------------------------------
// Chunked parallel scan, 3 phases.
// Phase A: per (chunk, col): zero-init local scan, LOAD-ONLY, emit f32 carry.
// ---------------------------------------------------------------------------
__global__ __launch_bounds__(256) void scanA_k(const u16* __restrict__ buf,
                                               const float* __restrict__ a_all,
                                               int layer,
                                               float* __restrict__ carry)
{
    const long T  = (long)blockIdx.x * 256 + threadIdx.x;  // 0 .. NC*COLS-1
    const int col = (int)(T & (COLS - 1));
    const int c   = (int)(T >> 17);
    const float av = a_all[layer * DH + (col & (DH - 1))];
    const u16* p = buf + (long)c * CL * COLS + col;

    float h = 0.f;
    float pre[8];
#pragma unroll
    for (int i = 0; i < 8; ++i) pre[i] = b2f(p[(long)i * COLS]);
    for (int s8 = 0; s8 < CL; s8 += 8) {
        const bool more = (s8 + 8) < CL;
#pragma unroll
        for (int j = 0; j < 8; ++j) {
            const float v = pre[j];
            if (more) pre[j] = b2f(p[(long)(s8 + 8 + j) * COLS]);
            h = fmaf(h, av, v);
        }
    }
    carry[T] = h;   // carry[c][col]
}

// ---------------------------------------------------------------------------
// Phase B: per col: sequential prefix over NC chunk carries (in-place:
// carry[c] becomes carry-IN of chunk c). pw = a^CL by repeated squaring.
// ---------------------------------------------------------------------------
__global__ __launch_bounds__(256) void scanB_k(float* __restrict__ carry,
                                               const float* __restrict__ a_all,
                                               int layer)
{
    const int col = blockIdx.x * 256 + threadIdx.x;       // 0..COLS-1
    const float av = a_all[layer * DH + (col & (DH - 1))];
    // a^56 = a^32 * a^16 * a^8
    float a2 = av * av, a4 = a2 * a2, a8 = a4 * a4;
    float a16 = a8 * a8, a32 = a16 * a16;
    const float pw = a32 * a16 * a8;

    float cin = 0.f;
    for (int c = 0; c < NC; ++c) {
        float cr = carry[(long)c * COLS + col];
        carry[(long)c * COLS + col] = cin;
        cin = fmaf(cin, pw, cr);
    }
}

// ---------------------------------------------------------------------------
// Phase C: per (chunk, col): h = carry_in; scan CL steps, write bf16 in place.
// ---------------------------------------------------------------------------
__global__ __launch_bounds__(256) void scanC_k(u16* __restrict__ buf,
                                               const float* __restrict__ a_all,
                                               int layer,
                                               const float* __restrict__ carry)
{
    const long T  = (long)blockIdx.x * 256 + threadIdx.x;
    const int col = (int)(T & (COLS - 1));
    const int c   = (int)(T >> 17);
    const float av = a_all[layer * DH + (col & (DH - 1))];
    u16* p = buf + (long)c * CL * COLS + col;

    float h = carry[T];
    float pre[8];
#pragma unroll
    for (int i = 0; i < 8; ++i) pre[i] = b2f(p[(long)i * COLS]);
    for (int s8 = 0; s8 < CL; s8 += 8) {
        const bool more = (s8 + 8) < CL;
#pragma unroll
        for (int j = 0; j < 8; ++j) {
            const float v = pre[j];
            if (more) pre[j] = b2f(p[(long)(s8 + 8 + j) * COLS]);
            h = fmaf(h, av, v);
            p[(long)(s8 + j) * COLS] = f2b(h);
        }
    }
}

// ---------------------------------------------------------------------------
// out[m] = dot(h[m,:], Wf) + bf + x[m]; one wave per row
// ---------------------------------------------------------------------------
__global__ __launch_bounds__(256) void final_k(const u16* __restrict__ h,
                                               const float* __restrict__ Wf,
                                               const float* __restrict__ bf_,
                                               const float* __restrict__ x,
                                               float* __restrict__ out)
{
    const long m  = (long)blockIdx.x * 4 + (threadIdx.x >> 6);
    const int lane = threadIdx.x & 63;
    const ushort8 v = *(const ushort8*)&h[m * DH + lane * 8];
    float s = 0.f;
#pragma unroll
    for (int j = 0; j < 8; ++j) s += b2f(v[j]) * Wf[lane * 8 + j];
#pragma unroll
    for (int off = 32; off > 0; off >>= 1) s += __shfl_down(s, off, 64);
    if (lane == 0) out[m] = s + bf_[0] + x[m];
}

// ---------------------------------------------------------------------------
extern "C" void kernel_launch(void* const* d_in, const int* in_sizes, int n_in,
                              void* d_out, int out_size, void* d_ws, size_t ws_size,
                              hipStream_t stream)
{
    const float* x   = (const float*)d_in[0];
    const float* W0  = (const float*)d_in[1];
    const float* b0  = (const float*)d_in[2];
    const float* a   = (const float*)d_in[3];
    const float* B   = (const float*)d_in[4];
    const float* C   = (const float*)d_in[5];
    const float* Wf  = (const float*)d_in[6];
    const float* bf_ = (const float*)d_in[7];
    float* out = (float*)d_out;

    // workspace: activation buffer (in-place) + packed bf16 weights + f32 carries
    const long BUF = (long)MT * DH;                  // 102,760,448 elements (u16)
    const size_t need = (size_t)BUF * 2 + 2ULL * 3 * DH * DH * 2
                      + (size_t)NC * COLS * 4;       // 216,006,656 B
    if (ws_size < need) return;  // diagnostic: zero output -> absmax == max|ref|

    u16*   buf   = (u16*)d_ws;
    u16*   Bp    = buf + BUF;
    u16*   Cp    = Bp + 3L * DH * DH;
    float* carry = (float*)(Cp + 3L * DH * DH);

    prep_k<<<(3 * DH * DH) / 256, 256, 0, stream>>>(B, C, Bp, Cp);
    h0_k<<<(MT * 64) / 256, 256, 0, stream>>>(x, W0, b0, buf);

    for (int l = 0; l < NL; ++l) {
        gemm_ip<0><<<MT / 64, 512, 0, stream>>>(buf, Bp + (long)l * DH * DH, buf);
        scanA_k<<<(NC * COLS) / 256, 256, 0, stream>>>(buf, a, l, carry);
        scanB_k<<<COLS / 256, 256, 0, stream>>>(carry, a, l);
        scanC_k<<<(NC * COLS) / 256, 256, 0, stream>>>(buf, a, l, carry);
        gemm_ip<1><<<MT / 64, 512, 0, stream>>>(buf, Cp + (long)l * DH * DH, buf);
    }
    final_k<<<MT / 4, 256, 0, stream>>>(buf, Wf, bf_, x, out);
}

// Round 7
// 940.733 us; speedup vs baseline: 1.1403x; 1.1403x over previous
//
#include <hip/hip_runtime.h>
#include <hip/hip_bf16.h>

// Problem constants (fixed by reference)
#define SEQ 784
#define BS  256
#define DH  512
#define MT  (SEQ * BS)   // 200704 rows
#define NL  3
#define NC  14           // scan chunks
#define CL  56           // chunk length (NC*CL == SEQ)
#define COLS (BS * DH)   // 131072 = 2^17

typedef unsigned short u16;
typedef __bf16  bf16x8  __attribute__((ext_vector_type(8)));
typedef float   f32x4   __attribute__((ext_vector_type(4)));
typedef unsigned short ushort8 __attribute__((ext_vector_type(8)));

__device__ __forceinline__ u16 f2b(float f) {
    unsigned int x = __float_as_uint(f);
    unsigned int r = (x + 0x7FFFu + ((x >> 16) & 1u)) >> 16;   // RNE
    return (u16)r;
}
__device__ __forceinline__ float b2f(u16 u) {
    return __uint_as_float(((unsigned int)u) << 16);
}

// ---------------------------------------------------------------------------
// prep: pack B[l],C[l] (f32 (l,k,n)) -> bf16 MFMA-fragment order:
//   n = wid*64 + ni*16 + (lane&15);  k = g*32 + (lane>>4)*8 + e
// so a wave's B-fragment load is one coalesced global_load_dwordx4.
// ---------------------------------------------------------------------------
__global__ __launch_bounds__(256) void prep_k(const float* __restrict__ B,
                                              const float* __restrict__ C,
                                              u16* __restrict__ Bp,
                                              u16* __restrict__ Cp)
{
    const long t = (long)blockIdx.x * 256 + threadIdx.x;   // 0 .. 3*2^18-1
    const int  e  = (int)(t & 7);
    const int  l  = (int)((t >> 3) & 63);
    const int  ni = (int)((t >> 9) & 3);
    const int  wd = (int)((t >> 11) & 7);
    const int  g  = (int)((t >> 14) & 15);
    const long lay = t >> 18;
    const int  n = wd * 64 + ni * 16 + (l & 15);
    const int  k = g * 32 + (l >> 4) * 8 + e;
    const long src = (lay << 18) + (long)k * DH + n;
    Bp[t] = f2b(B[src]);
    Cp[t] = f2b(C[src]);
}

// ===========================================================================
// GEMM family. Shared geometry: 64x512 tile, 8 waves (one 64x64 sub-tile
// each), mfma_f32_16x16x32_bf16; W fragment-packed (Bp/Cp) so B-operands are
// coalesced dwordx4 straight from L2; A panel in LDS with swizzle
//   slot s at row r holds logical chunk s^(r&7)   (bank-conflict-free, R4)
// Core K-loop = R5's per-step double-buffered stage (measured best: 116us).
// In-place safe: block owns rows [bm, bm+64) exclusively.
// ===========================================================================

// ---- standard middle GEMM (R5 exact) --------------------------------------
template <int RELU>
__global__ __launch_bounds__(512, 4) void gemm_ip(const u16* __restrict__ X,
                                                  const u16* __restrict__ Wp,
                                                  u16* __restrict__ Y)
{
    __shared__ __align__(16) u16 lds[64 * 512];   // 64 KB (A dbuf + C tile alias)

    const int tid  = threadIdx.x;
    const int lane = tid & 63;
    const int wid  = tid >> 6;
    const long bm  = (long)blockIdx.x * 64;

    const int srow = tid >> 3;
    const int scol = (((tid & 7) ^ (srow & 7)) * 8);
    const u16* gax = X + (bm + srow) * DH + scol;

    f32x4 acc[4][4];
#pragma unroll
    for (int i = 0; i < 4; ++i)
#pragma unroll
        for (int j = 0; j < 4; ++j)
            acc[i][j] = (f32x4){0.f, 0.f, 0.f, 0.f};

    __builtin_amdgcn_global_load_lds(
        (const __attribute__((address_space(1))) void*)gax,
        (__attribute__((address_space(3))) void*)
            ((__attribute__((address_space(3))) char*)lds + tid * 16),
        16, 0, 0);

    for (int t = 0; t < 8; ++t) {
        __syncthreads();
        if (t < 7) {
            __builtin_amdgcn_global_load_lds(
                (const __attribute__((address_space(1))) void*)(gax + (t + 1) * 64),
                (__attribute__((address_space(3))) void*)
                    ((__attribute__((address_space(3))) char*)lds +
                     ((t + 1) & 1) * 8192 + tid * 16),
                16, 0, 0);
        }
        const u16* Atile = lds + (t & 1) * 4096;

#pragma unroll
        for (int kk = 0; kk < 2; ++kk) {
            bf16x8 bv[4];
#pragma unroll
            for (int ni = 0; ni < 4; ++ni)
                bv[ni] = *(const bf16x8*)&Wp[((long)((2 * t + kk) * 32 + wid * 4 + ni) << 9)
                                             + (lane << 3)];
            const int fcol = ((kk * 4 + (lane >> 4)) ^ (lane & 7)) * 8;
            bf16x8 af[4];
#pragma unroll
            for (int i = 0; i < 4; ++i)
                af[i] = *(const bf16x8*)&Atile[(i * 16 + (lane & 15)) * 64 + fcol];
#pragma unroll
            for (int mi = 0; mi < 4; ++mi)
#pragma unroll
                for (int ni = 0; ni < 4; ++ni)
                    acc[mi][ni] = __builtin_amdgcn_mfma_f32_16x16x32_bf16(
                        af[mi], bv[ni], acc[mi][ni], 0, 0, 0);
        }
    }
    __syncthreads();

    // epilogue: C tile via LDS for coalesced stores (row-group swizzle)
    u16* Ctile = lds;
    const int rbase = (lane >> 4) * 4;
    const int cloc  = wid * 64 + (lane & 15);
#pragma unroll
    for (int mi = 0; mi < 4; ++mi)
#pragma unroll
        for (int ni = 0; ni < 4; ++ni)
#pragma unroll
            for (int r = 0; r < 4; ++r) {
                float v = acc[mi][ni][r];
                if (RELU) v = fmaxf(v, 0.f);
                const int row = mi * 16 + rbase + r;
                const int col = (cloc + ni * 16) ^ (((row >> 2) & 3) * 16);
                Ctile[row * 512 + col] = f2b(v);
            }
    __syncthreads();
#pragma unroll
    for (int p = 0; p < 8; ++p) {
        const int e   = p * 4096 + tid * 8;
        const int row = e >> 9;
        const int col = e & 511;
        const int csw = col ^ (((row >> 2) & 3) * 16);
        *(ushort8*)&Y[(bm + row) * DH + col] = *(const ushort8*)&Ctile[row * 512 + csw];
    }
}

// ---- layer-0 GEMM1 with fused h0: A panel COMPUTED in-LDS from x,W0,b0 ----
__global__ __launch_bounds__(512, 4) void gemm_first(const float* __restrict__ x,
                                                     const float* __restrict__ W0,
                                                     const float* __restrict__ b0,
                                                     const u16* __restrict__ Wp,
                                                     u16* __restrict__ Y)
{
    __shared__ __align__(16) u16 lds[64 * 512];   // full A panel, aliased C tile

    const int tid  = threadIdx.x;
    const int lane = tid & 63;
    const int wid  = tid >> 6;
    const long bm  = (long)blockIdx.x * 64;

    const int prow = tid >> 3;                 // panel row this thread fills
    const int slot = tid & 7;
    const float xv = x[bm + prow];

    // build the swizzled A panel: lds[t*4096 + prow*64 + slot*8 + e] holds
    // logical k = t*64 + (slot^(prow&7))*8 + e, value relu(xv*W0[k]+b0[k])
#pragma unroll
    for (int t = 0; t < 8; ++t) {
        const int k0 = t * 64 + ((slot ^ (prow & 7)) * 8);
        ushort8 o;
#pragma unroll
        for (int e = 0; e < 8; ++e)
            o[e] = f2b(fmaxf(fmaf(xv, W0[k0 + e], b0[k0 + e]), 0.f));
        *(ushort8*)&lds[t * 4096 + tid * 8] = o;
    }

    f32x4 acc[4][4];
#pragma unroll
    for (int i = 0; i < 4; ++i)
#pragma unroll
        for (int j = 0; j < 4; ++j)
            acc[i][j] = (f32x4){0.f, 0.f, 0.f, 0.f};

    __syncthreads();

#pragma unroll
    for (int t = 0; t < 8; ++t) {
        const u16* Atile = lds + t * 4096;
#pragma unroll
        for (int kk = 0; kk < 2; ++kk) {
            bf16x8 bv[4];
#pragma unroll
            for (int ni = 0; ni < 4; ++ni)
                bv[ni] = *(const bf16x8*)&Wp[((long)((2 * t + kk) * 32 + wid * 4 + ni) << 9)
                                             + (lane << 3)];
            const int fcol = ((kk * 4 + (lane >> 4)) ^ (lane & 7)) * 8;
            bf16x8 af[4];
#pragma unroll
            for (int i = 0; i < 4; ++i)
                af[i] = *(const bf16x8*)&Atile[(i * 16 + (lane & 15)) * 64 + fcol];
#pragma unroll
            for (int mi = 0; mi < 4; ++mi)
#pragma unroll
                for (int ni = 0; ni < 4; ++ni)
                    acc[mi][ni] = __builtin_amdgcn_mfma_f32_16x16x32_bf16(
                        af[mi], bv[ni], acc[mi][ni], 0, 0, 0);
        }
    }
    __syncthreads();

    u16* Ctile = lds;
    const int rbase = (lane >> 4) * 4;
    const int cloc  = wid * 64 + (lane & 15);
#pragma unroll
    for (int mi = 0; mi < 4; ++mi)
#pragma unroll
        for (int ni = 0; ni < 4; ++ni)
#pragma unroll
            for (int r = 0; r < 4; ++r) {
                const int row = mi * 16 + rbase + r;
                const int col = (cloc + ni * 16) ^ (((row >> 2) & 3) * 16);
                Ctile[row * 512 + col] = f2b(acc[mi][ni][r]);
            }
    __syncthreads();
#pragma unroll
    for (int p = 0; p < 8; ++p) {
        const int e   = p * 4096 + tid * 8;
        const int row = e >> 9;
        const int col = e & 511;
        const int csw = col ^ (((row >> 2) & 3) * 16);
        *(ushort8*)&Y[(bm + row) * DH + col] = *(const ushort8*)&Ctile[row * 512 + csw];
    }
}

// ---- layer-2 GEMM2 with fused final: out = relu(X@C)@Wf + bf + x ----------
__global__ __launch_bounds__(512, 4) void gemm_last(const u16* __restrict__ X,
                                                    const u16* __restrict__ Wp,
                                                    const float* __restrict__ Wf,
                                                    const float* __restrict__ bf_,
                                                    const float* __restrict__ x,
                                                    float* __restrict__ out)
{
    __shared__ __align__(16) u16 lds[64 * 512];
    float* partials = (float*)lds;             // [8][64] f32, used after K-loop

    const int tid  = threadIdx.x;
    const int lane = tid & 63;
    const int wid  = tid >> 6;
    const long bm  = (long)blockIdx.x * 64;

    const int srow = tid >> 3;
    const int scol = (((tid & 7) ^ (srow & 7)) * 8);
    const u16* gax = X + (bm + srow) * DH + scol;

    f32x4 acc[4][4];
#pragma unroll
    for (int i = 0; i < 4; ++i)
#pragma unroll
        for (int j = 0; j < 4; ++j)
            acc[i][j] = (f32x4){0.f, 0.f, 0.f, 0.f};

    __builtin_amdgcn_global_load_lds(
        (const __attribute__((address_space(1))) void*)gax,
        (__attribute__((address_space(3))) void*)
            ((__attribute__((address_space(3))) char*)lds + tid * 16),
        16, 0, 0);

    for (int t = 0; t < 8; ++t) {
        __syncthreads();
        if (t < 7) {
            __builtin_amdgcn_global_load_lds(
                (const __attribute__((address_space(1))) void*)(gax + (t + 1) * 64),
                (__attribute__((address_space(3))) void*)
                    ((__attribute__((address_space(3))) char*)lds +
                     ((t + 1) & 1) * 8192 + tid * 16),
                16, 0, 0);
        }
        const u16* Atile = lds + (t & 1) * 4096;

#pragma unroll
        for (int kk = 0; kk < 2; ++kk) {
            bf16x8 bv[4];
#pragma unroll
            for (int ni = 0; ni < 4; ++ni)
                bv[ni] = *(const bf16x8*)&Wp[((long)((2 * t + kk) * 32 + wid * 4 + ni) << 9)
                                             + (lane << 3)];
            const int fcol = ((kk * 4 + (lane >> 4)) ^ (lane & 7)) * 8;
            bf16x8 af[4];
#pragma unroll
            for (int i = 0; i < 4; ++i)
                af[i] = *(const bf16x8*)&Atile[(i * 16 + (lane & 15)) * 64 + fcol];
#pragma unroll
            for (int mi = 0; mi < 4; ++mi)
#pragma unroll
                for (int ni = 0; ni < 4; ++ni)
                    acc[mi][ni] = __builtin_amdgcn_mfma_f32_16x16x32_bf16(
                        af[mi], bv[ni], acc[mi][ni], 0, 0, 0);
        }
    }
    __syncthreads();   // done with A dbuf; lds reused as partials

    // fused epilogue: row-partial dot with Wf over this wave's 64-col slice
    const int cbase = wid * 64 + (lane & 15);
    float wf[4];
#pragma unroll
    for (int ni = 0; ni < 4; ++ni) wf[ni] = Wf[cbase + ni * 16];

    // part[mi][r] = sum_ni relu(acc)*wf ; rows = mi*16 + (lane>>4)*4 + r
    float part[4][4];
#pragma unroll
    for (int mi = 0; mi < 4; ++mi)
#pragma unroll
        for (int r = 0; r < 4; ++r) {
            float s = 0.f;
#pragma unroll
            for (int ni = 0; ni < 4; ++ni)
                s = fmaf(fmaxf(acc[mi][ni][r], 0.f), wf[ni], s);
            part[mi][r] = s;
        }
    // reduce over the 16 lanes (lane&15) that share the same rows
#pragma unroll
    for (int mi = 0; mi < 4; ++mi)
#pragma unroll
        for (int r = 0; r < 4; ++r) {
#pragma unroll
            for (int off = 1; off < 16; off <<= 1)
                part[mi][r] += __shfl_xor(part[mi][r], off, 64);
        }
    if ((lane & 15) == 0) {
        const int q = lane >> 4;
#pragma unroll
        for (int mi = 0; mi < 4; ++mi)
#pragma unroll
            for (int r = 0; r < 4; ++r)
                partials[wid * 64 + mi * 16 + q * 4 + r] = part[mi][r];
    }
    __syncthreads();
    if (tid < 64) {
        float s = 0.f;
#pragma unroll
        for (int w = 0; w < 8; ++w) s += partials[w * 64 + tid];
        out[bm + tid] = s + bf_[0] + x[bm + tid];
    }
}

// ---------------------------------------------------------------------------
// Chunked parallel scan, 3 phases (unchanged from R3).
// ---------------------------------------------------------------------------
__global__ __launch_bounds__(256) void scanA_k(const u16* __restrict__ buf,
                                               const float* __restrict__ a_all,
                                               int layer,
                                               float* __restrict__ carry)
{
    const long T  = (long)blockIdx.x * 256 + threadIdx.x;
    const int col = (int)(T & (COLS - 1));
    const int c   = (int)(T >> 17);
    const float av = a_all[layer * DH + (col & (DH - 1))];
    const u16* p = buf + (long)c * CL * COLS + col;

    float h = 0.f;
    float pre[8];
#pragma unroll
    for (int i = 0; i < 8; ++i) pre[i] = b2f(p[(long)i * COLS]);
    for (int s8 = 0; s8 < CL; s8 += 8) {
        const bool more = (s8 + 8) < CL;
#pragma unroll
        for (int j = 0; j < 8; ++j) {
            const float v = pre[j];
            if (more) pre[j] = b2f(p[(long)(s8 + 8 + j) * COLS]);
            h = fmaf(h, av, v);
        }
    }
    carry[T] = h;
}

__global__ __launch_bounds__(256) void scanB_k(float* __restrict__ carry,
                                               const float* __restrict__ a_all,
                                               int layer)
{
    const int col = blockIdx.x * 256 + threadIdx.x;
    const float av = a_all[layer * DH + (col & (DH - 1))];
    float a2 = av * av, a4 = a2 * a2, a8 = a4 * a4;
    float a16 = a8 * a8, a32 = a16 * a16;
    const float pw = a32 * a16 * a8;   // a^56

    float cin = 0.f;
    for (int c = 0; c < NC; ++c) {
        float cr = carry[(long)c * COLS + col];
        carry[(long)c * COLS + col] = cin;
        cin = fmaf(cin, pw, cr);
    }
}

__global__ __launch_bounds__(256) void scanC_k(u16* __restrict__ buf,
                                               const float* __restrict__ a_all,
                                               int layer,
                                               const float* __restrict__ carry)
{
    const long T  = (long)blockIdx.x * 256 + threadIdx.x;
    const int col = (int)(T & (COLS - 1));
    const int c   = (int)(T >> 17);
    const float av = a_all[layer * DH + (col & (DH - 1))];
    u16* p = buf + (long)c * CL * COLS + col;

    float h = carry[T];
    float pre[8];
#pragma unroll
    for (int i = 0; i < 8; ++i) pre[i] = b2f(p[(long)i * COLS]);
    for (int s8 = 0; s8 < CL; s8 += 8) {
        const bool more = (s8 + 8) < CL;
#pragma unroll
        for (int j = 0; j < 8; ++j) {
            const float v = pre[j];
            if (more) pre[j] = b2f(p[(long)(s8 + 8 + j) * COLS]);
            h = fmaf(h, av, v);
            p[(long)(s8 + j) * COLS] = f2b(h);
        }
    }
}

// ---------------------------------------------------------------------------
extern "C" void kernel_launch(void* const* d_in, const int* in_sizes, int n_in,
                              void* d_out, int out_size, void* d_ws, size_t ws_size,
                              hipStream_t stream)
{
    const float* x   = (const float*)d_in[0];
    const float* W0  = (const float*)d_in[1];
    const float* b0  = (const float*)d_in[2];
    const float* a   = (const float*)d_in[3];
    const float* B   = (const float*)d_in[4];
    const float* C   = (const float*)d_in[5];
    const float* Wf  = (const float*)d_in[6];
    const float* bf_ = (const float*)d_in[7];
    float* out = (float*)d_out;

    const long BUF = (long)MT * DH;                  // 102,760,448 elements (u16)
    const size_t need = (size_t)BUF * 2 + 2ULL * 3 * DH * DH * 2
                      + (size_t)NC * COLS * 4;       // 216,006,656 B
    if (ws_size < need) return;

    u16*   buf   = (u16*)d_ws;
    u16*   Bp    = buf + BUF;
    u16*   Cp    = Bp + 3L * DH * DH;
    float* carry = (float*)(Cp + 3L * DH * DH);

    prep_k<<<(3 * DH * DH) / 256, 256, 0, stream>>>(B, C, Bp, Cp);

    for (int l = 0; l < NL; ++l) {
        if (l == 0)
            gemm_first<<<MT / 64, 512, 0, stream>>>(x, W0, b0, Bp, buf);
        else
            gemm_ip<0><<<MT / 64, 512, 0, stream>>>(buf, Bp + (long)l * DH * DH, buf);

        scanA_k<<<(NC * COLS) / 256, 256, 0, stream>>>(buf, a, l, carry);
        scanB_k<<<COLS / 256, 256, 0, stream>>>(carry, a, l);
        scanC_k<<<(NC * COLS) / 256, 256, 0, stream>>>(buf, a, l, carry);

        if (l == NL - 1)
            gemm_last<<<MT / 64, 512, 0, stream>>>(buf, Cp + (long)l * DH * DH,
                                                   Wf, bf_, x, out);
        else
            gemm_ip<1><<<MT / 64, 512, 0, stream>>>(buf, Cp + (long)l * DH * DH, buf);
    }
}